// Round 8
// baseline (203.401 us; speedup 1.0000x reference)
//
#include <hip/hip_runtime.h>
#include <hip/hip_fp16.h>

#define NN 100000
#define HC 128
#define NE 1600000

typedef float f32x4 __attribute__((ext_vector_type(4)));
typedef short bf16x8 __attribute__((ext_vector_type(8)));

// round-to-nearest-even float -> bf16 (bit trick; inputs are tame, no NaN/Inf)
__device__ __forceinline__ unsigned short f2bf(float f) {
  union { float f; unsigned u; } c; c.f = f;
  unsigned u = c.u + (0x7FFFu + ((c.u >> 16) & 1u));
  return (unsigned short)(u >> 16);
}
__device__ __forceinline__ float bf2f(unsigned short b) {
  union { unsigned u; float f; } c; c.u = ((unsigned)b) << 16;
  return c.f;
}

// ---------------------------------------------------------------------------
// Prep A: split W into bf16 hi/lo, laid out [o][k] (o in [0,256), k in [0,128)):
//   o <  128 : src = W1[o][k]          (U weights)
//   o >= 128 : src = W1[o-128][128+k]  (V weights)
// ---------------------------------------------------------------------------
__global__ __launch_bounds__(256) void wprep_kernel(
    const float* __restrict__ W1, unsigned short* __restrict__ Wh,
    unsigned short* __restrict__ Wl) {
  const int idx = blockIdx.x * 256 + threadIdx.x;  // over 256*128
  if (idx >= 256 * 128) return;
  const int o = idx >> 7;
  const int k = idx & 127;
  const float f = W1[(size_t)(o & 127) * 256 + ((o >> 7) << 7) + k];
  const unsigned short hi = f2bf(f);
  Wh[idx] = hi;
  Wl[idx] = f2bf(f - bf2f(hi));
}

// ---------------------------------------------------------------------------
// Prep B: split z into bf16 hi/lo (pure streaming; coalesced 32B/thread).
// zh/zl layout [node][k], same as z.
// ---------------------------------------------------------------------------
__global__ __launch_bounds__(256) void zsplit_kernel(
    const float* __restrict__ z, unsigned short* __restrict__ zh,
    unsigned short* __restrict__ zl) {
  const int i = blockIdx.x * 256 + threadIdx.x;  // chunk of 8 floats
  if (i >= NN * HC / 8) return;
  const float4 p0 = ((const float4*)z)[2 * i];
  const float4 p1 = ((const float4*)z)[2 * i + 1];
  const float v[8] = {p0.x, p0.y, p0.z, p0.w, p1.x, p1.y, p1.z, p1.w};
  union { uint4 u; unsigned short s[8]; } ph, pl;
#pragma unroll
  for (int e = 0; e < 8; ++e) {
    const unsigned short hi = f2bf(v[e]);
    ph.s[e] = hi;
    pl.s[e] = f2bf(v[e] - bf2f(hi));
  }
  *(uint4*)(zh + (size_t)i * 8) = ph.u;
  *(uint4*)(zl + (size_t)i * 8) = pl.u;
}

// ---------------------------------------------------------------------------
// Stage 1 (MFMA bf16x3, pre-split inputs): D[m=o][n=node].
//   A-frag = W  : lane l holds W[o = nt*16 + (l&15)][k = (l>>4)*8 + e]
//   B-frag = z  : lane l holds z[node = base + (l&15)][k = (l>>4)*8 + e]
//   D:  lane l, reg r -> o = nt*16 + (l>>4)*4 + r, node = base + (l&15)
// Wave = 32 nodes x 256 outputs; block = 4 waves = 128 nodes.
// Fragment loads are direct bf16x8 (16B, rows contiguous in 64B chunks);
// no conversion VALU in this kernel. fp32 accuracy via Ah*Bh + Al*Bh + Ah*Bl.
// ---------------------------------------------------------------------------
__global__ __launch_bounds__(256) void precompute_uv_mfma3_kernel(
    const unsigned short* __restrict__ zh, const unsigned short* __restrict__ zl,
    const unsigned short* __restrict__ Wh, const unsigned short* __restrict__ Wl,
    __half* __restrict__ UV) {
  const int lane = threadIdx.x & 63;
  const int wv = threadIdx.x >> 6;              // wave 0..3
  const int nb = blockIdx.x * 128 + wv * 32;    // wave's node base
  const int lr = lane & 15;
  const int lg = lane >> 4;

  // ---- load z fragments (B): 2 node-subtiles x 4 k-groups, bf16 direct ----
  bf16x8 bh[2][4], bl[2][4];
#pragma unroll
  for (int ms = 0; ms < 2; ++ms) {
    const int node = nb + ms * 16 + lr;
    if (node < NN) {
      const bf16x8* __restrict__ ph = (const bf16x8*)(zh + (size_t)node * HC);
      const bf16x8* __restrict__ pl = (const bf16x8*)(zl + (size_t)node * HC);
#pragma unroll
      for (int kg = 0; kg < 4; ++kg) {
        bh[ms][kg] = ph[kg * 4 + lg];
        bl[ms][kg] = pl[kg * 4 + lg];
      }
    } else {
#pragma unroll
      for (int kg = 0; kg < 4; ++kg) {
        bh[ms][kg] = (bf16x8)(short)0;
        bl[ms][kg] = (bf16x8)(short)0;
      }
    }
  }

  // ---- loop over 16 output tiles of 16 ----
#pragma unroll 1
  for (int nt = 0; nt < 16; ++nt) {
    const unsigned short* __restrict__ wph = Wh + (nt * 16 + lr) * 128 + lg * 8;
    const unsigned short* __restrict__ wpl = Wl + (nt * 16 + lr) * 128 + lg * 8;

    f32x4 acc0 = {0.f, 0.f, 0.f, 0.f};   // node-subtile 0
    f32x4 acc1 = {0.f, 0.f, 0.f, 0.f};   // node-subtile 1
#pragma unroll
    for (int kg = 0; kg < 4; ++kg) {
      const bf16x8 ah = *(const bf16x8*)(wph + kg * 32);
      const bf16x8 al = *(const bf16x8*)(wpl + kg * 32);
      acc0 = __builtin_amdgcn_mfma_f32_16x16x32_bf16(ah, bh[0][kg], acc0, 0, 0, 0);
      acc0 = __builtin_amdgcn_mfma_f32_16x16x32_bf16(al, bh[0][kg], acc0, 0, 0, 0);
      acc0 = __builtin_amdgcn_mfma_f32_16x16x32_bf16(ah, bl[0][kg], acc0, 0, 0, 0);
      acc1 = __builtin_amdgcn_mfma_f32_16x16x32_bf16(ah, bh[1][kg], acc1, 0, 0, 0);
      acc1 = __builtin_amdgcn_mfma_f32_16x16x32_bf16(al, bh[1][kg], acc1, 0, 0, 0);
      acc1 = __builtin_amdgcn_mfma_f32_16x16x32_bf16(ah, bl[1][kg], acc1, 0, 0, 0);
    }

    // ---- packed store: lane holds o = nt*16 + lg*4 + (0..3) for its node ----
    const int ob = nt * 16 + lg * 4;
    {
      const int node = nb + lr;
      if (node < NN) {
        union { uint2 u; __half2 h[2]; } pk;
        pk.h[0] = __floats2half2_rn(acc0[0], acc0[1]);
        pk.h[1] = __floats2half2_rn(acc0[2], acc0[3]);
        *(uint2*)(UV + (size_t)node * 256 + ob) = pk.u;
      }
      const int node1 = nb + 16 + lr;
      if (node1 < NN) {
        union { uint2 u; __half2 h[2]; } pk;
        pk.h[0] = __floats2half2_rn(acc1[0], acc1[1]);
        pk.h[1] = __floats2half2_rn(acc1[2], acc1[3]);
        *(uint2*)(UV + (size_t)node1 * 256 + ob) = pk.u;
      }
    }
  }
}

// ---------------------------------------------------------------------------
// Stage 2: per-edge decode from fp16 UV (unchanged). 16 lanes per edge;
// lane l owns o = 8l..8l+7.
// ---------------------------------------------------------------------------
__global__ __launch_bounds__(256) void edge_decode_f16_kernel(
    const int* __restrict__ eidx, const __half* __restrict__ UV,
    const float* __restrict__ b1, const float* __restrict__ W2,
    const float* __restrict__ b2, float* __restrict__ out) {
  const int lane = threadIdx.x & 15;
  const int qw = (blockIdx.x * 256 + threadIdx.x) >> 4;
  const int nqw = (gridDim.x * 256) >> 4;

  const float4 b1a = ((const float4*)b1)[2 * lane];
  const float4 b1b = ((const float4*)b1)[2 * lane + 1];
  const float4 w2a = ((const float4*)W2)[2 * lane];
  const float4 w2b = ((const float4*)W2)[2 * lane + 1];
  const float bb[8] = {b1a.x, b1a.y, b1a.z, b1a.w, b1b.x, b1b.y, b1b.z, b1b.w};
  const float ww[8] = {w2a.x, w2a.y, w2a.z, w2a.w, w2b.x, w2b.y, w2b.z, w2b.w};
  const float bias2 = b2[0];

  const int* __restrict__ rows = eidx;
  const int* __restrict__ cols = eidx + NE;

#pragma unroll 2
  for (int e = qw; e < NE; e += nqw) {
    const int r = rows[e];
    const int c = cols[e];
    union { uint4 u; __half2 h[4]; } Uu, Vv;
    Uu.u = *(const uint4*)(UV + (size_t)r * 256 + lane * 8);
    Vv.u = *(const uint4*)(UV + (size_t)c * 256 + 128 + lane * 8);

    float s = 0.f;
#pragma unroll
    for (int k = 0; k < 4; ++k) {
      const float2 uf = __half22float2(Uu.h[k]);
      const float2 vf = __half22float2(Vv.h[k]);
      float t0 = uf.x + vf.x + bb[2 * k];
      t0 = (t0 >= 0.f) ? t0 : 0.01f * t0;
      s = fmaf(t0, ww[2 * k], s);
      float t1 = uf.y + vf.y + bb[2 * k + 1];
      t1 = (t1 >= 0.f) ? t1 : 0.01f * t1;
      s = fmaf(t1, ww[2 * k + 1], s);
    }

    s += __shfl_xor(s, 8);
    s += __shfl_xor(s, 4);
    s += __shfl_xor(s, 2);
    s += __shfl_xor(s, 1);
    if (lane == 0) out[e] = s + bias2;
  }
}

// ---------------------------------------------------------------------------
// Fallback (only if workspace is too small): direct per-edge fp32 compute.
// ---------------------------------------------------------------------------
__global__ __launch_bounds__(64) void edge_direct_kernel(
    const float* __restrict__ z, const int* __restrict__ eidx,
    const float* __restrict__ W1, const float* __restrict__ b1,
    const float* __restrict__ W2, const float* __restrict__ b2,
    float* __restrict__ out) {
  const int lane = threadIdx.x;
  const int o0 = lane, o1 = lane + 64;
  const float w2_0 = W2[o0], w2_1 = W2[o1];
  const float b1_0 = b1[o0], b1_1 = b1[o1];
  const float bias2 = b2[0];

  for (int e = blockIdx.x; e < NE; e += gridDim.x) {
    const int r = eidx[e];
    const int c = eidx[e + NE];
    const float* __restrict__ zr = z + (size_t)r * HC;
    const float* __restrict__ zc = z + (size_t)c * HC;
    float a0 = 0.f, a1 = 0.f;
    for (int h = 0; h < HC; ++h) {
      const float zrh = zr[h], zch = zc[h];
      a0 = fmaf(zrh, W1[(size_t)o0 * 256 + h], a0);
      a0 = fmaf(zch, W1[(size_t)o0 * 256 + 128 + h], a0);
      a1 = fmaf(zrh, W1[(size_t)o1 * 256 + h], a1);
      a1 = fmaf(zch, W1[(size_t)o1 * 256 + 128 + h], a1);
    }
    a0 += b1_0; a1 += b1_1;
    a0 = (a0 >= 0.f) ? a0 : 0.01f * a0;
    a1 = (a1 >= 0.f) ? a1 : 0.01f * a1;
    float s = fmaf(a0, w2_0, a1 * w2_1);
    for (int off = 32; off >= 1; off >>= 1) s += __shfl_xor(s, off);
    if (lane == 0) out[e] = s + bias2;
  }
}

extern "C" void kernel_launch(void* const* d_in, const int* in_sizes, int n_in,
                              void* d_out, int out_size, void* d_ws, size_t ws_size,
                              hipStream_t stream) {
  const float* z  = (const float*)d_in[0];
  const int*   ei = (const int*)d_in[1];
  const float* W1 = (const float*)d_in[2];
  const float* b1 = (const float*)d_in[3];
  const float* W2 = (const float*)d_in[4];
  const float* b2 = (const float*)d_in[5];
  float* out = (float*)d_out;

  const size_t uv_bytes = (size_t)NN * 256 * sizeof(__half);          // 51,200,000
  const size_t w_bytes  = (size_t)256 * 128 * sizeof(unsigned short); // 65,536 each
  const size_t z_bytes  = (size_t)NN * HC * sizeof(unsigned short);   // 25,600,000 each
  // total = 102,531,072 bytes == round-2's proven-available requirement

  if (ws_size >= uv_bytes + 2 * w_bytes + 2 * z_bytes) {
    __half* UV = (__half*)d_ws;
    unsigned short* Wh = (unsigned short*)((char*)d_ws + uv_bytes);
    unsigned short* Wl = Wh + 256 * 128;
    unsigned short* zh = Wl + 256 * 128;
    unsigned short* zl = zh + (size_t)NN * HC;
    wprep_kernel<<<128, 256, 0, stream>>>(W1, Wh, Wl);
    zsplit_kernel<<<(NN * HC / 8 + 255) / 256, 256, 0, stream>>>(z, zh, zl);
    precompute_uv_mfma3_kernel<<<(NN + 127) / 128, 256, 0, stream>>>(zh, zl, Wh, Wl, UV);
    edge_decode_f16_kernel<<<2048, 256, 0, stream>>>(ei, UV, b1, W2, b2, out);
  } else {
    edge_direct_kernel<<<8192, 64, 0, stream>>>(z, ei, W1, b1, W2, b2, out);
  }
}

// Round 9
// 190.736 us; speedup vs baseline: 1.0664x; 1.0664x over previous
//
#include <hip/hip_runtime.h>
#include <hip/hip_fp16.h>

#define NN 100000
#define HC 128
#define NE 1600000

typedef float f32x4 __attribute__((ext_vector_type(4)));
typedef short bf16x8 __attribute__((ext_vector_type(8)));

// round-to-nearest-even float -> bf16 (bit trick; inputs are tame, no NaN/Inf)
__device__ __forceinline__ unsigned short f2bf(float f) {
  union { float f; unsigned u; } c; c.f = f;
  unsigned u = c.u + (0x7FFFu + ((c.u >> 16) & 1u));
  return (unsigned short)(u >> 16);
}
__device__ __forceinline__ float bf2f(unsigned short b) {
  union { unsigned u; float f; } c; c.u = ((unsigned)b) << 16;
  return c.f;
}

// ---------------------------------------------------------------------------
// Prep: split W into bf16 hi/lo, laid out [o][k] (o in [0,256), k in [0,128)):
//   o <  128 : src = W1[o][k]          (U weights)
//   o >= 128 : src = W1[o-128][128+k]  (V weights)
// ---------------------------------------------------------------------------
__global__ __launch_bounds__(256) void wprep_kernel(
    const float* __restrict__ W1, unsigned short* __restrict__ Wh,
    unsigned short* __restrict__ Wl) {
  const int idx = blockIdx.x * 256 + threadIdx.x;  // over 256*128
  if (idx >= 256 * 128) return;
  const int o = idx >> 7;
  const int k = idx & 127;
  const float f = W1[(size_t)(o & 127) * 256 + ((o >> 7) << 7) + k];
  const unsigned short hi = f2bf(f);
  Wh[idx] = hi;
  Wl[idx] = f2bf(f - bf2f(hi));
}

// ---------------------------------------------------------------------------
// Stage 1 (MFMA bf16x3, WIDE grid): D[m=o][n=node].
// Block = 32 nodes x 256 outputs, 4 waves; wave wv covers outputs
// [wv*64, wv*64+64) for ALL 32 nodes (4 nt-tiles of 16) -> 12,500 waves
// (12.2/SIMD) instead of 3,128 (3.05/SIMD): latency-hiding via TLP.
// The 4 waves load the same z tile (16 KB) -> L1-served after first wave.
//   A-frag = W : lane l holds W[o][k=(l>>4)*8+e],  o-local = l&15
//   B-frag = z : lane l holds z[node][k],          node-local = l&15
//   D: lane l, reg r -> o-local = (l>>4)*4+r, node-local = l&15
// fp32 accuracy via split-bf16 (Ah*Bh + Al*Bh + Ah*Bl), packed fp16 store.
// NN % 32 == 0 -> no bounds checks.
// ---------------------------------------------------------------------------
__global__ __launch_bounds__(256) void precompute_uv_mfma4_kernel(
    const float* __restrict__ z, const unsigned short* __restrict__ Wh,
    const unsigned short* __restrict__ Wl, __half* __restrict__ UV) {
  const int lane = threadIdx.x & 63;
  const int wv = threadIdx.x >> 6;        // wave 0..3 -> output quarter
  const int nb = blockIdx.x * 32;         // block's node base
  const int og = wv * 64;                 // wave's output base
  const int lr = lane & 15;
  const int lg = lane >> 4;

  // ---- load z fragments (B): 2 node-subtiles x 4 k-groups, split hi/lo ----
  bf16x8 bh[2][4], bl[2][4];
#pragma unroll
  for (int ms = 0; ms < 2; ++ms) {
    const int node = nb + ms * 16 + lr;
    const float* __restrict__ zp = z + (size_t)node * HC + lg * 8;
#pragma unroll
    for (int kg = 0; kg < 4; ++kg) {
      const float4 p0 = *(const float4*)(zp + kg * 32);
      const float4 p1 = *(const float4*)(zp + kg * 32 + 4);
      const float v[8] = {p0.x, p0.y, p0.z, p0.w, p1.x, p1.y, p1.z, p1.w};
#pragma unroll
      for (int e = 0; e < 8; ++e) {
        const unsigned short hi = f2bf(v[e]);
        bh[ms][kg][e] = (short)hi;
        bl[ms][kg][e] = (short)f2bf(v[e] - bf2f(hi));
      }
    }
  }

  // ---- loop over this wave's 4 output tiles of 16 ----
#pragma unroll 1
  for (int nt = 0; nt < 4; ++nt) {
    const int orow = og + nt * 16 + lr;
    const unsigned short* __restrict__ wph = Wh + orow * 128 + lg * 8;
    const unsigned short* __restrict__ wpl = Wl + orow * 128 + lg * 8;

    f32x4 acc0 = {0.f, 0.f, 0.f, 0.f};   // node-subtile 0
    f32x4 acc1 = {0.f, 0.f, 0.f, 0.f};   // node-subtile 1
#pragma unroll
    for (int kg = 0; kg < 4; ++kg) {
      const bf16x8 ah = *(const bf16x8*)(wph + kg * 32);
      const bf16x8 al = *(const bf16x8*)(wpl + kg * 32);
      acc0 = __builtin_amdgcn_mfma_f32_16x16x32_bf16(ah, bh[0][kg], acc0, 0, 0, 0);
      acc0 = __builtin_amdgcn_mfma_f32_16x16x32_bf16(al, bh[0][kg], acc0, 0, 0, 0);
      acc0 = __builtin_amdgcn_mfma_f32_16x16x32_bf16(ah, bl[0][kg], acc0, 0, 0, 0);
      acc1 = __builtin_amdgcn_mfma_f32_16x16x32_bf16(ah, bh[1][kg], acc1, 0, 0, 0);
      acc1 = __builtin_amdgcn_mfma_f32_16x16x32_bf16(al, bh[1][kg], acc1, 0, 0, 0);
      acc1 = __builtin_amdgcn_mfma_f32_16x16x32_bf16(ah, bl[1][kg], acc1, 0, 0, 0);
    }

    // ---- packed store: lane holds o = og + nt*16 + lg*4 + (0..3) ----
    const int ob = og + nt * 16 + lg * 4;
    {
      const int node = nb + lr;
      union { uint2 u; __half2 h[2]; } pk;
      pk.h[0] = __floats2half2_rn(acc0[0], acc0[1]);
      pk.h[1] = __floats2half2_rn(acc0[2], acc0[3]);
      *(uint2*)(UV + (size_t)node * 256 + ob) = pk.u;
    }
    {
      const int node = nb + 16 + lr;
      union { uint2 u; __half2 h[2]; } pk;
      pk.h[0] = __floats2half2_rn(acc1[0], acc1[1]);
      pk.h[1] = __floats2half2_rn(acc1[2], acc1[3]);
      *(uint2*)(UV + (size_t)node * 256 + ob) = pk.u;
    }
  }
}

// ---------------------------------------------------------------------------
// Stage 2: per-edge decode from fp16 UV (unchanged). 16 lanes per edge;
// lane l owns o = 8l..8l+7.
// ---------------------------------------------------------------------------
__global__ __launch_bounds__(256) void edge_decode_f16_kernel(
    const int* __restrict__ eidx, const __half* __restrict__ UV,
    const float* __restrict__ b1, const float* __restrict__ W2,
    const float* __restrict__ b2, float* __restrict__ out) {
  const int lane = threadIdx.x & 15;
  const int qw = (blockIdx.x * 256 + threadIdx.x) >> 4;
  const int nqw = (gridDim.x * 256) >> 4;

  const float4 b1a = ((const float4*)b1)[2 * lane];
  const float4 b1b = ((const float4*)b1)[2 * lane + 1];
  const float4 w2a = ((const float4*)W2)[2 * lane];
  const float4 w2b = ((const float4*)W2)[2 * lane + 1];
  const float bb[8] = {b1a.x, b1a.y, b1a.z, b1a.w, b1b.x, b1b.y, b1b.z, b1b.w};
  const float ww[8] = {w2a.x, w2a.y, w2a.z, w2a.w, w2b.x, w2b.y, w2b.z, w2b.w};
  const float bias2 = b2[0];

  const int* __restrict__ rows = eidx;
  const int* __restrict__ cols = eidx + NE;

#pragma unroll 2
  for (int e = qw; e < NE; e += nqw) {
    const int r = rows[e];
    const int c = cols[e];
    union { uint4 u; __half2 h[4]; } Uu, Vv;
    Uu.u = *(const uint4*)(UV + (size_t)r * 256 + lane * 8);
    Vv.u = *(const uint4*)(UV + (size_t)c * 256 + 128 + lane * 8);

    float s = 0.f;
#pragma unroll
    for (int k = 0; k < 4; ++k) {
      const float2 uf = __half22float2(Uu.h[k]);
      const float2 vf = __half22float2(Vv.h[k]);
      float t0 = uf.x + vf.x + bb[2 * k];
      t0 = (t0 >= 0.f) ? t0 : 0.01f * t0;
      s = fmaf(t0, ww[2 * k], s);
      float t1 = uf.y + vf.y + bb[2 * k + 1];
      t1 = (t1 >= 0.f) ? t1 : 0.01f * t1;
      s = fmaf(t1, ww[2 * k + 1], s);
    }

    s += __shfl_xor(s, 8);
    s += __shfl_xor(s, 4);
    s += __shfl_xor(s, 2);
    s += __shfl_xor(s, 1);
    if (lane == 0) out[e] = s + bias2;
  }
}

// ---------------------------------------------------------------------------
// Fallback (only if workspace is too small): direct per-edge fp32 compute.
// ---------------------------------------------------------------------------
__global__ __launch_bounds__(64) void edge_direct_kernel(
    const float* __restrict__ z, const int* __restrict__ eidx,
    const float* __restrict__ W1, const float* __restrict__ b1,
    const float* __restrict__ W2, const float* __restrict__ b2,
    float* __restrict__ out) {
  const int lane = threadIdx.x;
  const int o0 = lane, o1 = lane + 64;
  const float w2_0 = W2[o0], w2_1 = W2[o1];
  const float b1_0 = b1[o0], b1_1 = b1[o1];
  const float bias2 = b2[0];

  for (int e = blockIdx.x; e < NE; e += gridDim.x) {
    const int r = eidx[e];
    const int c = eidx[e + NE];
    const float* __restrict__ zr = z + (size_t)r * HC;
    const float* __restrict__ zc = z + (size_t)c * HC;
    float a0 = 0.f, a1 = 0.f;
    for (int h = 0; h < HC; ++h) {
      const float zrh = zr[h], zch = zc[h];
      a0 = fmaf(zrh, W1[(size_t)o0 * 256 + h], a0);
      a0 = fmaf(zch, W1[(size_t)o0 * 256 + 128 + h], a0);
      a1 = fmaf(zrh, W1[(size_t)o1 * 256 + h], a1);
      a1 = fmaf(zch, W1[(size_t)o1 * 256 + 128 + h], a1);
    }
    a0 += b1_0; a1 += b1_1;
    a0 = (a0 >= 0.f) ? a0 : 0.01f * a0;
    a1 = (a1 >= 0.f) ? a1 : 0.01f * a1;
    float s = fmaf(a0, w2_0, a1 * w2_1);
    for (int off = 32; off >= 1; off >>= 1) s += __shfl_xor(s, off);
    if (lane == 0) out[e] = s + bias2;
  }
}

extern "C" void kernel_launch(void* const* d_in, const int* in_sizes, int n_in,
                              void* d_out, int out_size, void* d_ws, size_t ws_size,
                              hipStream_t stream) {
  const float* z  = (const float*)d_in[0];
  const int*   ei = (const int*)d_in[1];
  const float* W1 = (const float*)d_in[2];
  const float* b1 = (const float*)d_in[3];
  const float* W2 = (const float*)d_in[4];
  const float* b2 = (const float*)d_in[5];
  float* out = (float*)d_out;

  const size_t uv_bytes = (size_t)NN * 256 * sizeof(__half);          // 51,200,000
  const size_t w_bytes  = (size_t)256 * 128 * sizeof(unsigned short); // 65,536 each

  if (ws_size >= uv_bytes + 2 * w_bytes) {
    __half* UV = (__half*)d_ws;
    unsigned short* Wh = (unsigned short*)((char*)d_ws + uv_bytes);
    unsigned short* Wl = Wh + 256 * 128;
    wprep_kernel<<<128, 256, 0, stream>>>(W1, Wh, Wl);
    precompute_uv_mfma4_kernel<<<NN / 32, 256, 0, stream>>>(z, Wh, Wl, UV);
    edge_decode_f16_kernel<<<2048, 256, 0, stream>>>(ei, UV, b1, W2, b2, out);
  } else {
    edge_direct_kernel<<<8192, 64, 0, stream>>>(z, ei, W1, b1, W2, b2, out);
  }
}